// Round 9
// baseline (235.581 us; speedup 1.0000x reference)
//
#include <hip/hip_runtime.h>
#include <hip/hip_bf16.h>

// CausalSelfAttention: B=4, S=2048, C=1024, H=16, D=64
//   k1: single fused fp32->bf16 convert (x, qkv_w, proj_w)
//   k2: NT GEMM 128x128, global_load_lds(16B), XOR-swizzled LDS
//       -> Q [bh][s][d] (scaled 0.125*log2e), K [bh][s][d], V [bh][d][s]
//       r15: m204 bijective XCD swizzle — measured WIN (69.5->67.6 us,
//       FETCH 71.8->66-70 MB). Kept.
//       (r10 lesson: 256x256 8-phase port REGRESSED 70.7->83.9 us.)
//   k3: flash attention, BQ=128, ONE q-tile per block, 1024 blocks,
//       big q-tiles dispatched first; async double-buffered
//       global_load_lds staging; fixed-max exp2 softmax; swapped QK^T
//       (mfma(K,Q)); r13 in-register P transpose (cvt_pk + permlane
//       swap network), no LDS P slab, no lgkmcnt in k-loop.
//       (r15 lesson: s_setprio around MFMA clusters REGRESSED ~+6us —
//        our attn is a 4-wave barrier-synced block = m190's lockstep
//        regime where setprio is null-to-negative; m191's +4-7% was on
//        1-wave independent blocks. REVERTED.)
//   k4: NT GEMM 128x128 -> fp32 out + bias

typedef __attribute__((ext_vector_type(8))) short short8;
typedef __attribute__((ext_vector_type(4))) float floatx4;

__device__ __forceinline__ unsigned short f2b(float f) {
    union { float f; unsigned u; } x; x.f = f;
    unsigned r = (x.u + 0x7fffu + ((x.u >> 16) & 1u)) >> 16;  // RNE
    return (unsigned short)r;
}

__device__ __forceinline__ void load16_to_lds(const unsigned short* g, unsigned short* l) {
    auto gp = (const __attribute__((address_space(1))) unsigned int*)(unsigned long long)g;
    auto lp = (__attribute__((address_space(3))) unsigned int*)(unsigned int)(unsigned long long)l;
    __builtin_amdgcn_global_load_lds(gp, lp, 16, 0, 0);
}

// fused converts: x (2097152 f4), qkv_w (786432 f4), proj_w (262144 f4)
__global__ void __launch_bounds__(256)
convert_all(const float* __restrict__ x, const float* __restrict__ w1,
            const float* __restrict__ w2, unsigned short* __restrict__ xb,
            unsigned short* __restrict__ wb1, unsigned short* __restrict__ wb2) {
    const int N0 = 2097152, N1 = 786432;
    int i = blockIdx.x * 256 + threadIdx.x;
    const float* src; unsigned short* dst; int off;
    if (i < N0)           { src = x;  dst = xb;  off = i; }
    else if (i < N0 + N1) { src = w1; dst = wb1; off = i - N0; }
    else                  { src = w2; dst = wb2; off = i - N0 - N1; }
    float4 f = ((const float4*)src)[off];
    ushort4 u;
    u.x = f2b(f.x); u.y = f2b(f.y); u.z = f2b(f.z); u.w = f2b(f.w);
    ((ushort4*)dst)[off] = u;
}

// NT GEMM: C[m,n] = sum_k A[m,k] * Bw[n,k] + bias[n]
template<int MODE>
__global__ void __launch_bounds__(256)
gemm_nt(const unsigned short* __restrict__ A, const unsigned short* __restrict__ Bw,
        const float* __restrict__ bias, int M, int N, int K,
        unsigned short* __restrict__ Qo, unsigned short* __restrict__ Ko,
        unsigned short* __restrict__ Vo, float* __restrict__ Co) {
    __shared__ unsigned short As[128][64];   // unpadded, XOR-swizzled
    __shared__ unsigned short Bs[128][64];
    const int tid = threadIdx.x;
    const int wave = tid >> 6, lane = tid & 63;
    const int lane15 = lane & 15, quad = lane >> 4;
    const int waveM = wave >> 1, waveN = wave & 1;

    // m204 bijective XCD swizzle (nwg % 8 == 0 for both grids):
    // flat%8 = XCD under round-robin dispatch -> give each XCD a
    // contiguous chunk of logical blocks (A-panel reuse lands in one L2).
    const int nwg = gridDim.x * gridDim.y;
    const int flat = blockIdx.y * gridDim.x + blockIdx.x;
    const int wg = (flat & 7) * (nwg >> 3) + (flat >> 3);
    const int m0 = (wg / gridDim.x) * 128, n0 = (wg % gridDim.x) * 128;
    const int swz = (lane15 & 7);

    floatx4 acc[4][4];
#pragma unroll
    for (int i = 0; i < 4; ++i)
#pragma unroll
        for (int j = 0; j < 4; ++j) acc[i][j] = (floatx4){0.f, 0.f, 0.f, 0.f};

    for (int kt = 0; kt < K; kt += 64) {
        __syncthreads();
#pragma unroll
        for (int i = 0; i < 4; ++i) {
            int idx = tid + i * 256;            // 1024 16B-chunks per matrix
            int r = idx >> 3, c = idx & 7;
            int gc = (c ^ (r & 7)) * 8;
            load16_to_lds(&A[(size_t)(m0 + r) * K + kt + gc], &As[0][0] + idx * 8);
            load16_to_lds(&Bw[(size_t)(n0 + r) * K + kt + gc], &Bs[0][0] + idx * 8);
        }
        __asm__ volatile("s_waitcnt vmcnt(0)" ::: "memory");
        __syncthreads();
#pragma unroll
        for (int ks = 0; ks < 2; ++ks) {
            short8 af[4], bfr[4];
#pragma unroll
            for (int i = 0; i < 4; ++i)
                af[i] = *(const short8*)&As[waveM * 64 + i * 16 + lane15][((ks * 4 + quad) ^ swz) * 8];
#pragma unroll
            for (int j = 0; j < 4; ++j)
                bfr[j] = *(const short8*)&Bs[waveN * 64 + j * 16 + lane15][((ks * 4 + quad) ^ swz) * 8];
#pragma unroll
            for (int i = 0; i < 4; ++i)
#pragma unroll
                for (int j = 0; j < 4; ++j)
                    acc[i][j] = __builtin_amdgcn_mfma_f32_16x16x32_bf16(af[i], bfr[j], acc[i][j], 0, 0, 0);
        }
    }

    const float QSCALE = 0.18033688011112042f;  // 0.125 * log2(e)
    if (MODE == 0) {
        const int sel = n0 >> 10;               // block-uniform: 0=Q 1=K 2=V
#pragma unroll
        for (int i = 0; i < 4; ++i)
#pragma unroll
            for (int j = 0; j < 4; ++j) {
                const int n = n0 + waveN * 64 + j * 16 + lane15;
                const int c = n & 1023;
                const int h = c >> 6, d = c & 63;
                const float bia = bias[n];
                const int mbase = m0 + waveM * 64 + i * 16 + quad * 4;
                const int b = mbase >> 11, s = mbase & 2047;
                const size_t bh = (size_t)(b * 16 + h);
                if (sel == 2) {
                    // V [bh][d][s]: 4 consecutive s per lane -> ushort4
                    ushort4 w;
                    w.x = f2b(acc[i][j][0] + bia);
                    w.y = f2b(acc[i][j][1] + bia);
                    w.z = f2b(acc[i][j][2] + bia);
                    w.w = f2b(acc[i][j][3] + bia);
                    *(ushort4*)&Vo[(bh * 64 + d) * 2048 + s] = w;
                } else {
                    unsigned short* dst = (sel == 0) ? Qo : Ko;
                    const float sc = (sel == 0) ? QSCALE : 1.0f;
#pragma unroll
                    for (int r = 0; r < 4; ++r)
                        dst[(bh * 2048 + s + r) * 64 + d] = f2b((acc[i][j][r] + bia) * sc);
                }
            }
    } else {
#pragma unroll
        for (int i = 0; i < 4; ++i)
#pragma unroll
            for (int j = 0; j < 4; ++j)
#pragma unroll
                for (int r = 0; r < 4; ++r) {
                    int m = m0 + waveM * 64 + i * 16 + quad * 4 + r;
                    int n = n0 + waveN * 64 + j * 16 + lane15;
                    Co[(size_t)m * N + n] = acc[i][j][r] + bias[n];
                }
    }
}

// Flash attention: 1024 blocks (1D), block 256 (4 waves x 32 q-rows).
// One 128-row q-tile per block; big tiles dispatched first.
__global__ void __launch_bounds__(256, 2)
attn_kernel(const unsigned short* __restrict__ Q, const unsigned short* __restrict__ K,
            const unsigned short* __restrict__ V, unsigned short* __restrict__ O) {
    const int S = 2048, D = 64;
    __shared__ unsigned short Ks[2][64][64];   // [buf][key][d], swizzled
    __shared__ unsigned short Vt[2][64][64];   // [buf][d][key], swizzled

    // flat&7 -> XCD (round-robin dispatch). Each XCD owns 8 heads
    // (4MB KV = one L2). qb descends with flat: long k-loops dispatch
    // first so short ones backfill (dynamic load balance).
    const int flat = blockIdx.x;                      // 0..1023
    const int bh = (flat & 7) * 8 + ((flat >> 3) & 7);
    const int qb = 15 - (flat >> 6);                  // 15..0

    const int tid = threadIdx.x;
    const int wave = tid >> 6, lane = tid & 63;
    const int lane15 = lane & 15, quad = lane >> 4;
    const int swz = (lane15 & 7);

    const unsigned short* Qb = Q + (size_t)bh * S * D;
    const unsigned short* Kb = K + (size_t)bh * S * D;
    const unsigned short* Vb = V + (size_t)bh * D * S;  // [d][s]
    const int b = bh >> 4, h = bh & 15;

    auto stage = [&](int buf, int kb) {
#pragma unroll
        for (int i = 0; i < 2; ++i) {
            int idx = tid + i * 256;            // 512 16B-chunks per matrix
            int r = idx >> 3, c = idx & 7;
            int gc = (c ^ (r & 7)) * 8;
            load16_to_lds(&Kb[(size_t)(kb + r) * D + gc], &Ks[buf][0][0] + idx * 8);
            load16_to_lds(&Vb[(size_t)r * S + kb + gc], &Vt[buf][0][0] + idx * 8);
        }
    };

    const int q0 = qb * 128;
    const int ntiles = 2 * qb + 2;

    short8 qf[2][2];
#pragma unroll
    for (int mi = 0; mi < 2; ++mi) {
        int qrow = q0 + wave * 32 + mi * 16 + lane15;
#pragma unroll
        for (int ks = 0; ks < 2; ++ks)
            qf[mi][ks] = *(const short8*)&Qb[(size_t)qrow * D + ks * 32 + quad * 8];
    }

    floatx4 o[2][4];
    float l_acc[2];
#pragma unroll
    for (int mi = 0; mi < 2; ++mi) {
        l_acc[mi] = 0.f;
#pragma unroll
        for (int r = 0; r < 4; ++r) o[mi][r] = (floatx4){0.f, 0.f, 0.f, 0.f};
    }

    __syncthreads();
    stage(0, 0);                    // preload tile 0

    for (int kt = 0; kt < ntiles; ++kt) {
        const int cur = kt & 1;
        const int kb = kt * 64;
        __asm__ volatile("s_waitcnt vmcnt(0)" ::: "memory");  // own loads landed
        __syncthreads();                                       // all waves landed
        if (kt + 1 < ntiles) stage(1 - cur, kb + 64);          // async next tile

        // S^T = K Q^T (swapped): sa[mi][j][r] = score for
        //   key = kb + j*16 + quad*4 + r,  q = q0 + wave*32 + mi*16 + lane15
        floatx4 sa[2][4];
#pragma unroll
        for (int mi = 0; mi < 2; ++mi)
#pragma unroll
            for (int j = 0; j < 4; ++j) sa[mi][j] = (floatx4){0.f, 0.f, 0.f, 0.f};
#pragma unroll
        for (int j = 0; j < 4; ++j)
#pragma unroll
            for (int ks = 0; ks < 2; ++ks) {
                short8 kf = *(const short8*)&Ks[cur][j * 16 + lane15][((ks * 4 + quad) ^ swz) * 8];
#pragma unroll
                for (int mi = 0; mi < 2; ++mi)
                    sa[mi][j] = __builtin_amdgcn_mfma_f32_16x16x32_bf16(kf, qf[mi][ks], sa[mi][j], 0, 0, 0);
            }

        if (kb + 64 > q0) {         // diagonal tiles: causal mask
#pragma unroll
            for (int mi = 0; mi < 2; ++mi)
#pragma unroll
                for (int j = 0; j < 4; ++j)
#pragma unroll
                    for (int r = 0; r < 4; ++r) {
                        int key = kb + j * 16 + quad * 4 + r;
                        int qq = q0 + wave * 32 + mi * 16 + lane15;
                        if (key > qq) sa[mi][j][r] = -1e30f;
                    }
        }

        // fixed-max softmax: p = exp2(s); l lane-local per q-row.
        // P -> bf16 pairs (cvt_pk), then in-register quad redistribution:
        //   swap32(a,c);swap16(a,c) -> a=[a0,a2,c0,c2]=w0, c=[a1,a3,c1,c3]=w2
        //   (ISA-verified); (b,d)->(w1,w3).
        short8 pf[2][2];
#pragma unroll
        for (int mi = 0; mi < 2; ++mi) {
#pragma unroll
            for (int j = 0; j < 4; ++j)
#pragma unroll
                for (int r = 0; r < 4; ++r)
                    sa[mi][j][r] = __builtin_amdgcn_exp2f(sa[mi][j][r]);
#pragma unroll
            for (int j = 0; j < 4; ++j)
                l_acc[mi] += (sa[mi][j][0] + sa[mi][j][1]) + (sa[mi][j][2] + sa[mi][j][3]);
            unsigned pk0[4], pk1[4];
#pragma unroll
            for (int j = 0; j < 4; ++j) {
                __asm__("v_cvt_pk_bf16_f32 %0, %1, %2"
                        : "=v"(pk0[j]) : "v"(sa[mi][j][0]), "v"(sa[mi][j][1]));
                __asm__("v_cvt_pk_bf16_f32 %0, %1, %2"
                        : "=v"(pk1[j]) : "v"(sa[mi][j][2]), "v"(sa[mi][j][3]));
            }
#pragma unroll
            for (int ks = 0; ks < 2; ++ks) {
                unsigned a = pk0[2 * ks], b = pk1[2 * ks];
                unsigned c = pk0[2 * ks + 1], d = pk1[2 * ks + 1];
                __asm__("v_permlane32_swap_b32 %0, %1" : "+v"(a), "+v"(c));
                __asm__("v_permlane16_swap_b32 %0, %1" : "+v"(a), "+v"(c));
                __asm__("v_permlane32_swap_b32 %0, %1" : "+v"(b), "+v"(d));
                __asm__("v_permlane16_swap_b32 %0, %1" : "+v"(b), "+v"(d));
                union { unsigned u[4]; short8 s; } pu;
                pu.u[0] = a; pu.u[1] = b; pu.u[2] = c; pu.u[3] = d;
                pf[mi][ks] = pu.s;
            }
        }

        // O += P V
#pragma unroll
        for (int jd = 0; jd < 4; ++jd)
#pragma unroll
            for (int ks = 0; ks < 2; ++ks) {
                short8 vf = *(const short8*)&Vt[cur][jd * 16 + lane15][((ks * 4 + quad) ^ swz) * 8];
#pragma unroll
                for (int mi = 0; mi < 2; ++mi)
                    o[mi][jd] = __builtin_amdgcn_mfma_f32_16x16x32_bf16(pf[mi][ks], vf, o[mi][jd], 0, 0, 0);
            }
    }

    // l reduction: sum the 4 quads (each lane holds partial for q=lane15)
#pragma unroll
    for (int mi = 0; mi < 2; ++mi) {
        l_acc[mi] += __shfl_xor(l_acc[mi], 16);
        l_acc[mi] += __shfl_xor(l_acc[mi], 32);
    }

#pragma unroll
    for (int mi = 0; mi < 2; ++mi)
#pragma unroll
        for (int r = 0; r < 4; ++r) {
            int qq = q0 + wave * 32 + mi * 16 + quad * 4 + r;
            // fetch l for q=quad*4+r (held by lanes with lane15==quad*4+r)
            float lq = __shfl(l_acc[mi], (lane & 48) + quad * 4 + r);
            float inv = 1.0f / lq;
#pragma unroll
            for (int jd = 0; jd < 4; ++jd)
                O[((size_t)(b * 2048 + qq)) * 1024 + h * 64 + jd * 16 + lane15] =
                    f2b(o[mi][jd][r] * inv);
        }
}

extern "C" void kernel_launch(void* const* d_in, const int* in_sizes, int n_in,
                              void* d_out, int out_size, void* d_ws, size_t ws_size,
                              hipStream_t stream) {
    const float* x      = (const float*)d_in[0];
    const float* qkv_w  = (const float*)d_in[1];
    const float* qkv_b  = (const float*)d_in[2];
    const float* proj_w = (const float*)d_in[3];
    const float* proj_b = (const float*)d_in[4];
    float* out = (float*)d_out;

    const int B = 4, S = 2048, C = 1024, M = B * S;

    char* ws = (char*)d_ws;
    size_t off = 0;
    auto alloc = [&](size_t bytes) {
        void* p = ws + off;
        off += (bytes + 255) & ~(size_t)255;
        return p;
    };
    unsigned short* xb    = (unsigned short*)alloc((size_t)M * C * 2);
    unsigned short* wqkv  = (unsigned short*)alloc((size_t)3 * C * C * 2);
    unsigned short* wproj = (unsigned short*)alloc((size_t)C * C * 2);
    unsigned short* Qb    = (unsigned short*)alloc((size_t)M * C * 2);
    unsigned short* Kb    = (unsigned short*)alloc((size_t)M * C * 2);
    unsigned short* Vb    = (unsigned short*)alloc((size_t)M * C * 2);
    unsigned short* attn  = (unsigned short*)alloc((size_t)M * C * 2);

    {
        int total4 = (M * C + 3 * C * C + C * C) / 4;  // 3145728
        convert_all<<<total4 / 256, 256, 0, stream>>>(x, qkv_w, proj_w, xb, wqkv, wproj);
    }

    gemm_nt<0><<<dim3(3 * C / 128, M / 128), 256, 0, stream>>>(
        xb, wqkv, qkv_b, M, 3 * C, C, Qb, Kb, Vb, nullptr);

    attn_kernel<<<dim3(1024), 256, 0, stream>>>(Qb, Kb, Vb, attn);

    gemm_nt<1><<<dim3(C / 128, M / 128), 256, 0, stream>>>(
        attn, wproj, proj_b, M, C, C, nullptr, nullptr, nullptr, out);
}

// Round 10
// 221.742 us; speedup vs baseline: 1.0624x; 1.0624x over previous
//
#include <hip/hip_runtime.h>
#include <hip/hip_bf16.h>

// CausalSelfAttention: B=4, S=2048, C=1024, H=16, D=64
//   k1: single fused fp32->bf16 convert (x, qkv_w, proj_w)
//   k2: NT GEMM 128x128, global_load_lds(16B), XOR-swizzled LDS
//       -> Q [bh][s][d] (scaled 0.125*log2e), K [bh][s][d], V [bh][d][s]
//       r15: m204 bijective XCD swizzle (FETCH 71.8->66-70 MB, kept;
//       time delta within cross-run noise).
//   k3: flash attention, BQ=128, ONE q-tile per block, 1024 blocks;
//       async double-buffered global_load_lds staging; fixed-max exp2
//       softmax; swapped QK^T (mfma(K,Q)); r13 in-register P transpose
//       (cvt_pk + permlane swap network), no LDS P slab.
//       r17a: per-CU qb balance — 1024 blocks = exactly 4/CU, no backfill;
//       old monotone qb gave per-CU iter totals 56..80. perm[] makes every
//       stride-4 set sum to 30 -> every CU gets 68 iters.
//       r17b: l-sum via MFMA vs all-ones B (VALU->MFMA pipe): deletes
//       24 v_add/iter AND the epilogue shfl dance (l lands in D-layout
//       row=quad*4+r). Attn is VALU-issue-bound; MFMA pipe has slack.
//       (r15/r16 lesson: setprio & cross-run deltas <2% are noise here.)
//   k4: NT GEMM 128x128 -> fp32 out + bias

typedef __attribute__((ext_vector_type(8))) short short8;
typedef __attribute__((ext_vector_type(4))) float floatx4;

__device__ __forceinline__ unsigned short f2b(float f) {
    union { float f; unsigned u; } x; x.f = f;
    unsigned r = (x.u + 0x7fffu + ((x.u >> 16) & 1u)) >> 16;  // RNE
    return (unsigned short)r;
}

__device__ __forceinline__ void load16_to_lds(const unsigned short* g, unsigned short* l) {
    auto gp = (const __attribute__((address_space(1))) unsigned int*)(unsigned long long)g;
    auto lp = (__attribute__((address_space(3))) unsigned int*)(unsigned int)(unsigned long long)l;
    __builtin_amdgcn_global_load_lds(gp, lp, 16, 0, 0);
}

// fused converts: x (2097152 f4), qkv_w (786432 f4), proj_w (262144 f4)
__global__ void __launch_bounds__(256)
convert_all(const float* __restrict__ x, const float* __restrict__ w1,
            const float* __restrict__ w2, unsigned short* __restrict__ xb,
            unsigned short* __restrict__ wb1, unsigned short* __restrict__ wb2) {
    const int N0 = 2097152, N1 = 786432;
    int i = blockIdx.x * 256 + threadIdx.x;
    const float* src; unsigned short* dst; int off;
    if (i < N0)           { src = x;  dst = xb;  off = i; }
    else if (i < N0 + N1) { src = w1; dst = wb1; off = i - N0; }
    else                  { src = w2; dst = wb2; off = i - N0 - N1; }
    float4 f = ((const float4*)src)[off];
    ushort4 u;
    u.x = f2b(f.x); u.y = f2b(f.y); u.z = f2b(f.z); u.w = f2b(f.w);
    ((ushort4*)dst)[off] = u;
}

// NT GEMM: C[m,n] = sum_k A[m,k] * Bw[n,k] + bias[n]
template<int MODE>
__global__ void __launch_bounds__(256)
gemm_nt(const unsigned short* __restrict__ A, const unsigned short* __restrict__ Bw,
        const float* __restrict__ bias, int M, int N, int K,
        unsigned short* __restrict__ Qo, unsigned short* __restrict__ Ko,
        unsigned short* __restrict__ Vo, float* __restrict__ Co) {
    __shared__ unsigned short As[128][64];   // unpadded, XOR-swizzled
    __shared__ unsigned short Bs[128][64];
    const int tid = threadIdx.x;
    const int wave = tid >> 6, lane = tid & 63;
    const int lane15 = lane & 15, quad = lane >> 4;
    const int waveM = wave >> 1, waveN = wave & 1;

    // m204 bijective XCD swizzle (nwg % 8 == 0 for both grids):
    // flat%8 = XCD under round-robin dispatch -> give each XCD a
    // contiguous chunk of logical blocks (A-panel reuse lands in one L2).
    const int nwg = gridDim.x * gridDim.y;
    const int flat = blockIdx.y * gridDim.x + blockIdx.x;
    const int wg = (flat & 7) * (nwg >> 3) + (flat >> 3);
    const int m0 = (wg / gridDim.x) * 128, n0 = (wg % gridDim.x) * 128;
    const int swz = (lane15 & 7);

    floatx4 acc[4][4];
#pragma unroll
    for (int i = 0; i < 4; ++i)
#pragma unroll
        for (int j = 0; j < 4; ++j) acc[i][j] = (floatx4){0.f, 0.f, 0.f, 0.f};

    for (int kt = 0; kt < K; kt += 64) {
        __syncthreads();
#pragma unroll
        for (int i = 0; i < 4; ++i) {
            int idx = tid + i * 256;            // 1024 16B-chunks per matrix
            int r = idx >> 3, c = idx & 7;
            int gc = (c ^ (r & 7)) * 8;
            load16_to_lds(&A[(size_t)(m0 + r) * K + kt + gc], &As[0][0] + idx * 8);
            load16_to_lds(&Bw[(size_t)(n0 + r) * K + kt + gc], &Bs[0][0] + idx * 8);
        }
        __asm__ volatile("s_waitcnt vmcnt(0)" ::: "memory");
        __syncthreads();
#pragma unroll
        for (int ks = 0; ks < 2; ++ks) {
            short8 af[4], bfr[4];
#pragma unroll
            for (int i = 0; i < 4; ++i)
                af[i] = *(const short8*)&As[waveM * 64 + i * 16 + lane15][((ks * 4 + quad) ^ swz) * 8];
#pragma unroll
            for (int j = 0; j < 4; ++j)
                bfr[j] = *(const short8*)&Bs[waveN * 64 + j * 16 + lane15][((ks * 4 + quad) ^ swz) * 8];
#pragma unroll
            for (int i = 0; i < 4; ++i)
#pragma unroll
                for (int j = 0; j < 4; ++j)
                    acc[i][j] = __builtin_amdgcn_mfma_f32_16x16x32_bf16(af[i], bfr[j], acc[i][j], 0, 0, 0);
        }
    }

    const float QSCALE = 0.18033688011112042f;  // 0.125 * log2(e)
    if (MODE == 0) {
        const int sel = n0 >> 10;               // block-uniform: 0=Q 1=K 2=V
#pragma unroll
        for (int i = 0; i < 4; ++i)
#pragma unroll
            for (int j = 0; j < 4; ++j) {
                const int n = n0 + waveN * 64 + j * 16 + lane15;
                const int c = n & 1023;
                const int h = c >> 6, d = c & 63;
                const float bia = bias[n];
                const int mbase = m0 + waveM * 64 + i * 16 + quad * 4;
                const int b = mbase >> 11, s = mbase & 2047;
                const size_t bh = (size_t)(b * 16 + h);
                if (sel == 2) {
                    // V [bh][d][s]: 4 consecutive s per lane -> ushort4
                    ushort4 w;
                    w.x = f2b(acc[i][j][0] + bia);
                    w.y = f2b(acc[i][j][1] + bia);
                    w.z = f2b(acc[i][j][2] + bia);
                    w.w = f2b(acc[i][j][3] + bia);
                    *(ushort4*)&Vo[(bh * 64 + d) * 2048 + s] = w;
                } else {
                    unsigned short* dst = (sel == 0) ? Qo : Ko;
                    const float sc = (sel == 0) ? QSCALE : 1.0f;
#pragma unroll
                    for (int r = 0; r < 4; ++r)
                        dst[(bh * 2048 + s + r) * 64 + d] = f2b((acc[i][j][r] + bia) * sc);
                }
            }
    } else {
#pragma unroll
        for (int i = 0; i < 4; ++i)
#pragma unroll
            for (int j = 0; j < 4; ++j)
#pragma unroll
                for (int r = 0; r < 4; ++r) {
                    int m = m0 + waveM * 64 + i * 16 + quad * 4 + r;
                    int n = n0 + waveN * 64 + j * 16 + lane15;
                    Co[(size_t)m * N + n] = acc[i][j][r] + bias[n];
                }
    }
}

// Flash attention: 1024 blocks (1D), block 256 (4 waves x 32 q-rows).
// One 128-row q-tile per block; qb interleaved so every CU's 4 resident
// blocks total exactly 68 k-iters (stride-4 columns of qperm sum to 30).
__global__ void __launch_bounds__(256, 2)
attn_kernel(const unsigned short* __restrict__ Q, const unsigned short* __restrict__ K,
            const unsigned short* __restrict__ V, unsigned short* __restrict__ O) {
    const int S = 2048, D = 64;
    __shared__ unsigned short Ks[2][64][64];   // [buf][key][d], swizzled
    __shared__ unsigned short Vt[2][64][64];   // [buf][d][key], swizzled

    // flat&7 -> XCD (round-robin dispatch). Each XCD owns 8 heads
    // (4MB KV = one L2). qb via balanced interleave: any 4 blocks spaced
    // 256 apart (one CU's residency set) sum to 2*30+8 = 68 iters.
    const int qperm[16] = {15,13,11,9, 0,2,4,6, 14,12,10,8, 1,3,5,7};
    const int flat = blockIdx.x;                      // 0..1023
    const int bh = (flat & 7) * 8 + ((flat >> 3) & 7);
    const int qb = qperm[flat >> 6];

    const int tid = threadIdx.x;
    const int wave = tid >> 6, lane = tid & 63;
    const int lane15 = lane & 15, quad = lane >> 4;
    const int swz = (lane15 & 7);

    const unsigned short* Qb = Q + (size_t)bh * S * D;
    const unsigned short* Kb = K + (size_t)bh * S * D;
    const unsigned short* Vb = V + (size_t)bh * D * S;  // [d][s]
    const int b = bh >> 4, h = bh & 15;

    auto stage = [&](int buf, int kb) {
#pragma unroll
        for (int i = 0; i < 2; ++i) {
            int idx = tid + i * 256;            // 512 16B-chunks per matrix
            int r = idx >> 3, c = idx & 7;
            int gc = (c ^ (r & 7)) * 8;
            load16_to_lds(&Kb[(size_t)(kb + r) * D + gc], &Ks[buf][0][0] + idx * 8);
            load16_to_lds(&Vb[(size_t)r * S + kb + gc], &Vt[buf][0][0] + idx * 8);
        }
    };

    const int q0 = qb * 128;
    const int ntiles = 2 * qb + 2;

    short8 qf[2][2];
#pragma unroll
    for (int mi = 0; mi < 2; ++mi) {
        int qrow = q0 + wave * 32 + mi * 16 + lane15;
#pragma unroll
        for (int ks = 0; ks < 2; ++ks)
            qf[mi][ks] = *(const short8*)&Qb[(size_t)qrow * D + ks * 32 + quad * 8];
    }

    // all-ones bf16 fragment for the l-sum MFMA (B=1 -> row sums of P)
    short8 ones8;
#pragma unroll
    for (int i = 0; i < 8; ++i) ones8[i] = (short)0x3F80;

    floatx4 o[2][4];
    floatx4 l_mf[2];
#pragma unroll
    for (int mi = 0; mi < 2; ++mi) {
        l_mf[mi] = (floatx4){0.f, 0.f, 0.f, 0.f};
#pragma unroll
        for (int r = 0; r < 4; ++r) o[mi][r] = (floatx4){0.f, 0.f, 0.f, 0.f};
    }

    __syncthreads();
    stage(0, 0);                    // preload tile 0

    for (int kt = 0; kt < ntiles; ++kt) {
        const int cur = kt & 1;
        const int kb = kt * 64;
        __asm__ volatile("s_waitcnt vmcnt(0)" ::: "memory");  // own loads landed
        __syncthreads();                                       // all waves landed
        if (kt + 1 < ntiles) stage(1 - cur, kb + 64);          // async next tile

        // S^T = K Q^T (swapped): sa[mi][j][r] = score for
        //   key = kb + j*16 + quad*4 + r,  q = q0 + wave*32 + mi*16 + lane15
        floatx4 sa[2][4];
#pragma unroll
        for (int mi = 0; mi < 2; ++mi)
#pragma unroll
            for (int j = 0; j < 4; ++j) sa[mi][j] = (floatx4){0.f, 0.f, 0.f, 0.f};
#pragma unroll
        for (int j = 0; j < 4; ++j)
#pragma unroll
            for (int ks = 0; ks < 2; ++ks) {
                short8 kf = *(const short8*)&Ks[cur][j * 16 + lane15][((ks * 4 + quad) ^ swz) * 8];
#pragma unroll
                for (int mi = 0; mi < 2; ++mi)
                    sa[mi][j] = __builtin_amdgcn_mfma_f32_16x16x32_bf16(kf, qf[mi][ks], sa[mi][j], 0, 0, 0);
            }

        if (kb + 64 > q0) {         // diagonal tiles: causal mask
#pragma unroll
            for (int mi = 0; mi < 2; ++mi)
#pragma unroll
                for (int j = 0; j < 4; ++j)
#pragma unroll
                    for (int r = 0; r < 4; ++r) {
                        int key = kb + j * 16 + quad * 4 + r;
                        int qq = q0 + wave * 32 + mi * 16 + lane15;
                        if (key > qq) sa[mi][j][r] = -1e30f;
                    }
        }

        // fixed-max softmax: p = exp2(s).
        // P -> bf16 pairs (cvt_pk), then in-register quad redistribution:
        //   swap32(a,c);swap16(a,c) -> a=[a0,a2,c0,c2]=w0, c=[a1,a3,c1,c3]=w2
        //   (ISA-verified); (b,d)->(w1,w3).
        short8 pf[2][2];
#pragma unroll
        for (int mi = 0; mi < 2; ++mi) {
#pragma unroll
            for (int j = 0; j < 4; ++j)
#pragma unroll
                for (int r = 0; r < 4; ++r)
                    sa[mi][j][r] = __builtin_amdgcn_exp2f(sa[mi][j][r]);
            unsigned pk0[4], pk1[4];
#pragma unroll
            for (int j = 0; j < 4; ++j) {
                __asm__("v_cvt_pk_bf16_f32 %0, %1, %2"
                        : "=v"(pk0[j]) : "v"(sa[mi][j][0]), "v"(sa[mi][j][1]));
                __asm__("v_cvt_pk_bf16_f32 %0, %1, %2"
                        : "=v"(pk1[j]) : "v"(sa[mi][j][2]), "v"(sa[mi][j][3]));
            }
#pragma unroll
            for (int ks = 0; ks < 2; ++ks) {
                unsigned a = pk0[2 * ks], b = pk1[2 * ks];
                unsigned c = pk0[2 * ks + 1], d = pk1[2 * ks + 1];
                __asm__("v_permlane32_swap_b32 %0, %1" : "+v"(a), "+v"(c));
                __asm__("v_permlane16_swap_b32 %0, %1" : "+v"(a), "+v"(c));
                __asm__("v_permlane32_swap_b32 %0, %1" : "+v"(b), "+v"(d));
                __asm__("v_permlane16_swap_b32 %0, %1" : "+v"(b), "+v"(d));
                union { unsigned u[4]; short8 s; } pu;
                pu.u[0] = a; pu.u[1] = b; pu.u[2] = c; pu.u[3] = d;
                pf[mi][ks] = pu.s;
            }
        }

        // O += P V ; l += P * 1 (row sums on the MFMA pipe; D-layout
        // row = quad*4+r matches the epilogue directly, no shuffles)
#pragma unroll
        for (int jd = 0; jd < 4; ++jd)
#pragma unroll
            for (int ks = 0; ks < 2; ++ks) {
                short8 vf = *(const short8*)&Vt[cur][jd * 16 + lane15][((ks * 4 + quad) ^ swz) * 8];
#pragma unroll
                for (int mi = 0; mi < 2; ++mi)
                    o[mi][jd] = __builtin_amdgcn_mfma_f32_16x16x32_bf16(pf[mi][ks], vf, o[mi][jd], 0, 0, 0);
            }
#pragma unroll
        for (int mi = 0; mi < 2; ++mi)
#pragma unroll
            for (int ks = 0; ks < 2; ++ks)
                l_mf[mi] = __builtin_amdgcn_mfma_f32_16x16x32_bf16(pf[mi][ks], ones8, l_mf[mi], 0, 0, 0);
    }

#pragma unroll
    for (int mi = 0; mi < 2; ++mi)
#pragma unroll
        for (int r = 0; r < 4; ++r) {
            int qq = q0 + wave * 32 + mi * 16 + quad * 4 + r;
            float inv = 1.0f / l_mf[mi][r];
#pragma unroll
            for (int jd = 0; jd < 4; ++jd)
                O[((size_t)(b * 2048 + qq)) * 1024 + h * 64 + jd * 16 + lane15] =
                    f2b(o[mi][jd][r] * inv);
        }
}

extern "C" void kernel_launch(void* const* d_in, const int* in_sizes, int n_in,
                              void* d_out, int out_size, void* d_ws, size_t ws_size,
                              hipStream_t stream) {
    const float* x      = (const float*)d_in[0];
    const float* qkv_w  = (const float*)d_in[1];
    const float* qkv_b  = (const float*)d_in[2];
    const float* proj_w = (const float*)d_in[3];
    const float* proj_b = (const float*)d_in[4];
    float* out = (float*)d_out;

    const int B = 4, S = 2048, C = 1024, M = B * S;

    char* ws = (char*)d_ws;
    size_t off = 0;
    auto alloc = [&](size_t bytes) {
        void* p = ws + off;
        off += (bytes + 255) & ~(size_t)255;
        return p;
    };
    unsigned short* xb    = (unsigned short*)alloc((size_t)M * C * 2);
    unsigned short* wqkv  = (unsigned short*)alloc((size_t)3 * C * C * 2);
    unsigned short* wproj = (unsigned short*)alloc((size_t)C * C * 2);
    unsigned short* Qb    = (unsigned short*)alloc((size_t)M * C * 2);
    unsigned short* Kb    = (unsigned short*)alloc((size_t)M * C * 2);
    unsigned short* Vb    = (unsigned short*)alloc((size_t)M * C * 2);
    unsigned short* attn  = (unsigned short*)alloc((size_t)M * C * 2);

    {
        int total4 = (M * C + 3 * C * C + C * C) / 4;  // 3145728
        convert_all<<<total4 / 256, 256, 0, stream>>>(x, qkv_w, proj_w, xb, wqkv, wproj);
    }

    gemm_nt<0><<<dim3(3 * C / 128, M / 128), 256, 0, stream>>>(
        xb, wqkv, qkv_b, M, 3 * C, C, Qb, Kb, Vb, nullptr);

    attn_kernel<<<dim3(1024), 256, 0, stream>>>(Qb, Kb, Vb, attn);

    gemm_nt<1><<<dim3(C / 128, M / 128), 256, 0, stream>>>(
        attn, wproj, proj_b, M, C, C, nullptr, nullptr, nullptr, out);
}